// Round 2
// baseline (616.430 us; speedup 1.0000x reference)
//
#include <hip/hip_runtime.h>

// Problem constants (QLinear_17918603559229)
#define TOKENS 8192
#define IN_F   4096
#define OUT_F  4096
#define GK     IN_F
#define GN     OUT_F

// 256x256 tile, BK=64, 8 waves (2M x 4N), 8-phase counted-vmcnt schedule (T3+T4+T5)
#define BM 256
#define BN 256
#define BK 64
#define NT (GK / BK)   // 64 K-tiles

typedef __attribute__((ext_vector_type(8))) short bf16x8;
typedef __attribute__((ext_vector_type(4))) float f32x4;
typedef __attribute__((address_space(1))) void gvoid;
typedef __attribute__((address_space(3))) void lvoid;

static __device__ __forceinline__ unsigned short f32_to_bf16(float f) {
  union { float f; unsigned int u; } v; v.f = f;
  unsigned int u = v.u;
  return (unsigned short)((u + 0x7FFFu + ((u >> 16) & 1u)) >> 16);  // RNE
}

// ---------------- fused prep: cast x (f32->bf16) + build W (bf16) ----------------
// blocks [0, 16384): cast 8 elems/thread; blocks [16384, 32768): build 4 elems/thread
__global__ void prep_kernel(const float4* __restrict__ x, bf16x8* __restrict__ xb,
                            const float* __restrict__ a, const float* __restrict__ s,
                            unsigned short* __restrict__ wb) {
  const int bid = blockIdx.x;
  if (bid < 16384) {
    const int idx = bid * 256 + threadIdx.x;
    float4 v0 = x[idx * 2];
    float4 v1 = x[idx * 2 + 1];
    bf16x8 r;
    r[0] = (short)f32_to_bf16(v0.x); r[1] = (short)f32_to_bf16(v0.y);
    r[2] = (short)f32_to_bf16(v0.z); r[3] = (short)f32_to_bf16(v0.w);
    r[4] = (short)f32_to_bf16(v1.x); r[5] = (short)f32_to_bf16(v1.y);
    r[6] = (short)f32_to_bf16(v1.z); r[7] = (short)f32_to_bf16(v1.w);
    xb[idx] = r;
  } else {
    const int gid = (bid - 16384) * 256 + threadIdx.x;   // OUT_F * IN_F / 4 threads
    const int o = gid >> 10;
    const int i = (gid & 1023) << 2;                      // 4 consecutive i, same j-block
    const int ib = o >> 10, p = o & 1023;
    const int jb = i >> 10, q = i & 1023;
    float r0 = 0.f, r1 = 0.f, r2 = 0.f, r3 = 0.f;
#pragma unroll
    for (int k = 0; k < 4; ++k) {
      float ak = a[k * 16 + ib * 4 + jb];
      const float4 sv = *(const float4*)(s + (((size_t)(k * 1024 + p)) << 10) + q);
      r0 += ak * sv.x; r1 += ak * sv.y; r2 += ak * sv.z; r3 += ak * sv.w;
    }
    ushort4 w;
    w.x = f32_to_bf16(r0); w.y = f32_to_bf16(r1);
    w.z = f32_to_bf16(r2); w.w = f32_to_bf16(r3);
    *(ushort4*)(wb + ((size_t)o << 12) + i) = w;
  }
}

// ---------------- GEMM: C[M,N] = A[M,K] @ B[N,K]^T + bias ----------------
// 256^2 8-phase schedule. Per K-tile t (buf p = t&1), 4 phases (one C-quadrant each):
//   phase 0: stage A0(t+1)->buf p^1; vmcnt(6); barrier; ds_read B(8)+Aq0(4); lgkmcnt(0); 16 MFMA; barrier
//   phase 1: ds_read Aq1; stage A1(t+1);           barrier; lgkmcnt(0); 16 MFMA; barrier
//   phase 2: ds_read Aq2; stage B0(t+2)->buf p;    barrier; lgkmcnt(0); 16 MFMA; barrier
//   phase 3: ds_read Aq3; stage B1(t+2)->buf p;    barrier; lgkmcnt(0); 16 MFMA; barrier
// Safety: B of buf p is fully read at phase 0 (barrier-separated before B(t+2) stages land);
// A of buf p^1 last read at tile t-1 phase 3. vmcnt(6) = 3 newest half-tiles left in flight,
// retiring exactly A(t) (staged at t-1.q0/q1) and B(t) (staged at t-2.q2/q3).
// Swizzle (zero-conflict, proven in prior kernel): LDS[row][g] = G[row][g ^ (row&7)],
// granule = 16B; linear LDS dest for global_load_lds, inverse-swizzled global source.
#define BARRIER() do { __builtin_amdgcn_s_barrier(); asm volatile("" ::: "memory"); } while (0)

__global__ __launch_bounds__(512, 2)
void gemm_bias_kernel(const unsigned short* __restrict__ A,
                      const unsigned short* __restrict__ B,
                      const float* __restrict__ bias,
                      float* __restrict__ C) {
  __shared__ unsigned short As[2][BM * BK];   // 2 x 32 KB
  __shared__ unsigned short Bs[2][BN * BK];   // 2 x 32 KB  (total 128 KB)

  const int tid  = threadIdx.x;
  const int lane = tid & 63;
  const int wave = tid >> 6;           // 0..7
  const int wr   = wave >> 2;          // 0..1  (M dim)
  const int wc   = wave & 3;           // 0..3  (N dim)
  const int m0 = blockIdx.y * BM;
  const int n0 = blockIdx.x * BN;

  const int ln15 = lane & 15;
  const int quad = lane >> 4;
  const int sw   = ln15 & 7;           // frag row & 7
  int ck[2];
  ck[0] = ((0 + quad) ^ sw) << 3;      // swizzled column (elems) for kk=0
  ck[1] = ((4 + quad) ^ sw) << 3;      // kk=1

  unsigned short* Asb = &As[0][0];
  unsigned short* Bsb = &Bs[0][0];

  // staging: thread covers rows (tid>>3)+{0,64} of a 128-row half, granule tid&7 (swizzled src)
  const int srow = tid >> 3;
  const int sgr  = (tid & 7) ^ (srow & 7);
  const unsigned short* Ag = A + (size_t)(m0 + srow) * GK + sgr * 8;
  const unsigned short* Bg = B + (size_t)(n0 + srow) * GK + sgr * 8;

#define STAGE_A(par, h, u) do { \
    const unsigned short* s_ = Ag + (size_t)((h) * 128) * GK + (u) * BK; \
    unsigned short* d_ = Asb + (par) * 16384 + (h) * 8192 + tid * 8; \
    __builtin_amdgcn_global_load_lds((const gvoid*)s_, (lvoid*)d_, 16, 0, 0); \
    __builtin_amdgcn_global_load_lds((const gvoid*)(s_ + (size_t)64 * GK), (lvoid*)(d_ + 4096), 16, 0, 0); \
  } while (0)

#define STAGE_B(par, h, u) do { \
    const unsigned short* s_ = Bg + (size_t)((h) * 128) * GK + (u) * BK; \
    unsigned short* d_ = Bsb + (par) * 16384 + (h) * 8192 + tid * 8; \
    __builtin_amdgcn_global_load_lds((const gvoid*)s_, (lvoid*)d_, 16, 0, 0); \
    __builtin_amdgcn_global_load_lds((const gvoid*)(s_ + (size_t)64 * GK), (lvoid*)(d_ + 4096), 16, 0, 0); \
  } while (0)

  f32x4 acc[8][4];
#pragma unroll
  for (int mi = 0; mi < 8; ++mi)
#pragma unroll
    for (int ni = 0; ni < 4; ++ni)
      acc[mi][ni] = (f32x4){0.f, 0.f, 0.f, 0.f};

  // read bases (element offsets into a buffer)
  const int aBase = wr * 8192 + ln15 * 64;                       // wave's A half + frag row
  const int bBase = (wc >> 1) * 8192 + ((wc & 1) * 64 + ln15) * 64;

  bf16x8 bfr[4][2];  // B frags: [ni][kk], held across the 4 phases of a tile

  // prologue: 6 half-tiles = 12 loads in flight: B(0)->buf0, A(0)->buf0, B(1)->buf1
  STAGE_B(0, 0, 0); STAGE_B(0, 1, 0);
  STAGE_A(0, 0, 0); STAGE_A(0, 1, 0);
  STAGE_B(1, 0, 1); STAGE_B(1, 1, 1);

  for (int t = 0; t < NT; ++t) {
    const int p  = t & 1;
    const int u1 = (t + 1 < NT) ? t + 1 : NT - 1;   // clamp: dead loads into correct dead buffer
    const int u2 = (t + 2 < NT) ? t + 2 : NT - 1;
    const unsigned short* Ard = Asb + p * 16384 + aBase;
    const unsigned short* Brd = Bsb + p * 16384 + bBase;

    // ---------------- phase 0 (quadrant 0, tile boundary) ----------------
    STAGE_A(p ^ 1, 0, u1);
    asm volatile("s_waitcnt vmcnt(6)" ::: "memory");   // retire A(t), B(t); keep 3 halves in flight
    BARRIER();
    {
      bf16x8 af[2][2];
#pragma unroll
      for (int ni = 0; ni < 4; ++ni)
#pragma unroll
        for (int kk = 0; kk < 2; ++kk)
          bfr[ni][kk] = *(const bf16x8*)(Brd + ni * 1024 + ck[kk]);
#pragma unroll
      for (int mi2 = 0; mi2 < 2; ++mi2)
#pragma unroll
        for (int kk = 0; kk < 2; ++kk)
          af[mi2][kk] = *(const bf16x8*)(Ard + mi2 * 1024 + ck[kk]);
      asm volatile("s_waitcnt lgkmcnt(0)" ::: "memory");
      __builtin_amdgcn_s_setprio(1);
#pragma unroll
      for (int kk = 0; kk < 2; ++kk)
#pragma unroll
        for (int mi2 = 0; mi2 < 2; ++mi2)
#pragma unroll
          for (int ni = 0; ni < 4; ++ni)
            acc[mi2][ni] = __builtin_amdgcn_mfma_f32_16x16x32_bf16(af[mi2][kk], bfr[ni][kk],
                                                                   acc[mi2][ni], 0, 0, 0);
      __builtin_amdgcn_s_setprio(0);
      BARRIER();
    }

    // ---------------- phases 1..3 (quadrants 1..3) ----------------
#pragma unroll
    for (int q = 1; q < 4; ++q) {
      bf16x8 af[2][2];
#pragma unroll
      for (int mi2 = 0; mi2 < 2; ++mi2)
#pragma unroll
        for (int kk = 0; kk < 2; ++kk)
          af[mi2][kk] = *(const bf16x8*)(Ard + (2 * q + mi2) * 1024 + ck[kk]);
      if (q == 1)      STAGE_A(p ^ 1, 1, u1);
      else if (q == 2) STAGE_B(p, 0, u2);
      else             STAGE_B(p, 1, u2);
      BARRIER();
      asm volatile("s_waitcnt lgkmcnt(0)" ::: "memory");
      __builtin_amdgcn_s_setprio(1);
#pragma unroll
      for (int kk = 0; kk < 2; ++kk)
#pragma unroll
        for (int mi2 = 0; mi2 < 2; ++mi2)
#pragma unroll
          for (int ni = 0; ni < 4; ++ni)
            acc[2 * q + mi2][ni] = __builtin_amdgcn_mfma_f32_16x16x32_bf16(af[mi2][kk], bfr[ni][kk],
                                                                           acc[2 * q + mi2][ni], 0, 0, 0);
      __builtin_amdgcn_s_setprio(0);
      BARRIER();
    }
  }

  // epilogue: C/D layout col = lane&15, row = quad*4 + reg  [m89/m91 verified]
#pragma unroll
  for (int ni = 0; ni < 4; ++ni) {
    const int col = n0 + wc * 64 + ni * 16 + ln15;
    const float bv = bias[col];
#pragma unroll
    for (int mi = 0; mi < 8; ++mi) {
      const int rowb = m0 + wr * 128 + mi * 16 + quad * 4;
#pragma unroll
      for (int r = 0; r < 4; ++r)
        C[(size_t)(rowb + r) * GN + col] = acc[mi][ni][r] + bv;
    }
  }
#undef STAGE_A
#undef STAGE_B
}

// ---------------- naive fallback (only if ws too small) ----------------
__global__ void naive_kernel(const float* __restrict__ x, const float* __restrict__ a,
                             const float* __restrict__ s, const float* __restrict__ bias,
                             float* __restrict__ out) {
  long long idx = (long long)blockIdx.x * blockDim.x + threadIdx.x;
  if (idx >= (long long)TOKENS * OUT_F) return;
  int t = (int)(idx >> 12);
  int o = (int)(idx & 4095);
  int ib = o >> 10, p = o & 1023;
  float acc = bias[o];
  for (int jb = 0; jb < 4; ++jb) {
    float a0 = a[0  + ib * 4 + jb];
    float a1 = a[16 + ib * 4 + jb];
    float a2 = a[32 + ib * 4 + jb];
    float a3 = a[48 + ib * 4 + jb];
    const float* xr = x + (size_t)t * IN_F + jb * 1024;
    const float* s0 = s + (size_t)p * 1024;
    const float* s1 = s0 + 1048576;
    const float* s2 = s1 + 1048576;
    const float* s3 = s2 + 1048576;
    for (int q = 0; q < 1024; ++q) {
      float w = a0 * s0[q] + a1 * s1[q] + a2 * s2[q] + a3 * s3[q];
      acc += xr[q] * w;
    }
  }
  out[idx] = acc;
}

extern "C" void kernel_launch(void* const* d_in, const int* in_sizes, int n_in,
                              void* d_out, int out_size, void* d_ws, size_t ws_size,
                              hipStream_t stream) {
  const float* x    = (const float*)d_in[0];
  const float* a    = (const float*)d_in[1];
  const float* s    = (const float*)d_in[2];
  const float* bias = (const float*)d_in[3];
  float* out = (float*)d_out;

  const size_t xb_elems = (size_t)TOKENS * IN_F;          // 33.5M bf16 = 67 MB
  const size_t wb_elems = (size_t)OUT_F * IN_F;           // 16.7M bf16 = 33.5 MB
  const size_t need = (xb_elems + wb_elems) * sizeof(unsigned short);

  if (ws_size >= need) {
    unsigned short* Xb = (unsigned short*)d_ws;
    unsigned short* Wb = Xb + xb_elems;
    const int cast_blocks  = (int)(xb_elems / 8 / 256);   // 16384
    const int build_blocks = (int)(wb_elems / 4 / 256);   // 16384
    prep_kernel<<<cast_blocks + build_blocks, 256, 0, stream>>>(
        (const float4*)x, (bf16x8*)Xb, a, s, Wb);
    dim3 grid(GN / BN, TOKENS / BM);                      // (16, 32) = 512 blocks
    gemm_bias_kernel<<<grid, 512, 0, stream>>>(Xb, Wb, bias, out);
  } else {
    long long total = (long long)TOKENS * OUT_F;
    naive_kernel<<<(int)((total + 255) / 256), 256, 0, stream>>>(x, a, s, bias, out);
  }
}

// Round 3
// 581.962 us; speedup vs baseline: 1.0592x; 1.0592x over previous
//
#include <hip/hip_runtime.h>

// Problem constants (QLinear_17918603559229)
#define TOKENS 8192
#define IN_F   4096
#define OUT_F  4096
#define GK     IN_F
#define GN     OUT_F

// 256x256 tile, BK=64, 8 waves (2M x 4N), 4-phase/tile counted-vmcnt schedule (T2+T3+T4+T5)
#define BM 256
#define BN 256
#define BK 64
#define NT (GK / BK)   // 64 K-tiles

typedef __attribute__((ext_vector_type(8))) short bf16x8;
typedef __attribute__((ext_vector_type(4))) float f32x4;
typedef __attribute__((address_space(1))) void gvoid;
typedef __attribute__((address_space(3))) void lvoid;

static __device__ __forceinline__ unsigned short f32_to_bf16(float f) {
  union { float f; unsigned int u; } v; v.f = f;
  unsigned int u = v.u;
  return (unsigned short)((u + 0x7FFFu + ((u >> 16) & 1u)) >> 16);  // RNE
}

// ---------------- fused prep: cast x (f32->bf16) + build W (bf16) ----------------
__global__ void prep_kernel(const float4* __restrict__ x, bf16x8* __restrict__ xb,
                            const float* __restrict__ a, const float* __restrict__ s,
                            unsigned short* __restrict__ wb) {
  const int bid = blockIdx.x;
  if (bid < 16384) {
    const int idx = bid * 256 + threadIdx.x;
    float4 v0 = x[idx * 2];
    float4 v1 = x[idx * 2 + 1];
    bf16x8 r;
    r[0] = (short)f32_to_bf16(v0.x); r[1] = (short)f32_to_bf16(v0.y);
    r[2] = (short)f32_to_bf16(v0.z); r[3] = (short)f32_to_bf16(v0.w);
    r[4] = (short)f32_to_bf16(v1.x); r[5] = (short)f32_to_bf16(v1.y);
    r[6] = (short)f32_to_bf16(v1.z); r[7] = (short)f32_to_bf16(v1.w);
    xb[idx] = r;
  } else {
    const int gid = (bid - 16384) * 256 + threadIdx.x;   // OUT_F * IN_F / 4 threads
    const int o = gid >> 10;
    const int i = (gid & 1023) << 2;
    const int ib = o >> 10, p = o & 1023;
    const int jb = i >> 10, q = i & 1023;
    float r0 = 0.f, r1 = 0.f, r2 = 0.f, r3 = 0.f;
#pragma unroll
    for (int k = 0; k < 4; ++k) {
      float ak = a[k * 16 + ib * 4 + jb];
      const float4 sv = *(const float4*)(s + (((size_t)(k * 1024 + p)) << 10) + q);
      r0 += ak * sv.x; r1 += ak * sv.y; r2 += ak * sv.z; r3 += ak * sv.w;
    }
    ushort4 w;
    w.x = f32_to_bf16(r0); w.y = f32_to_bf16(r1);
    w.z = f32_to_bf16(r2); w.w = f32_to_bf16(r3);
    *(ushort4*)(wb + ((size_t)o << 12) + i) = w;
  }
}

// ---------------- GEMM: C[M,N] = A[M,K] @ B[N,K]^T + bias ----------------
// Per K-tile t (buf p = t&1), 4 phases, ALL ds_reads issued PRE-barrier (template-faithful):
//   ph0: ds_read B(8)+Aq0(4) [buf p valid: prev tile's vmcnt(4)+barrier]; STAGE_A(t+1)h0;
//        barrier; setprio(1) 16 MFMA setprio(0); barrier
//   ph1: ds_read Aq1; STAGE_A(t+1)h1; barrier; MFMA; barrier
//   ph2: ds_read Aq2; STAGE_B(t+2)h0; barrier; MFMA; barrier
//   ph3: ds_read Aq3; STAGE_B(t+2)h1; barrier; MFMA; vmcnt(4); barrier
// vmcnt ledger (2 loads/STAGE): prologue 12 in flight, vmcnt(4) retires B(0),A(0).
// Each tile pushes 8; ph3 vmcnt(4) retires B(t+1),A(t+1), leaves B(t+2) (4) in flight.
// lgkm waits: NONE explicit — compiler emits counted waits from dataflow (m97 evidence).
// Swizzle: LDS[row][g] = G[row][g ^ (row&7)], 16B granules; linear LDS dest for
// global_load_lds + inverse-swizzled global source + swizzled ds_read (rule #21).
#define BARRIER() do { __builtin_amdgcn_s_barrier(); asm volatile("" ::: "memory"); } while (0)

__global__ __launch_bounds__(512, 2)
void gemm_bias_kernel(const unsigned short* __restrict__ A,
                      const unsigned short* __restrict__ B,
                      const float* __restrict__ bias,
                      float* __restrict__ C) {
  __shared__ unsigned short As[2][BM * BK];   // 2 x 32 KB
  __shared__ unsigned short Bs[2][BN * BK];   // 2 x 32 KB  (total 128 KB)

  const int tid  = threadIdx.x;
  const int lane = tid & 63;
  const int wave = tid >> 6;           // 0..7
  const int wr   = wave >> 2;          // 0..1  (M dim)
  const int wc   = wave & 3;           // 0..3  (N dim)
  const int m0 = blockIdx.y * BM;
  const int n0 = blockIdx.x * BN;

  const int ln15 = lane & 15;
  const int quad = lane >> 4;
  const int sw   = ln15 & 7;           // frag row & 7
  int ck[2];
  ck[0] = ((0 + quad) ^ sw) << 3;      // swizzled column (elems) for kk=0
  ck[1] = ((4 + quad) ^ sw) << 3;      // kk=1

  unsigned short* Asb = &As[0][0];
  unsigned short* Bsb = &Bs[0][0];

  // staging: thread covers rows (tid>>3)+{0,64} of a 128-row half, granule tid&7 (swizzled src)
  const int srow = tid >> 3;
  const int sgr  = (tid & 7) ^ (srow & 7);
  const unsigned short* Ag = A + (size_t)(m0 + srow) * GK + sgr * 8;
  const unsigned short* Bg = B + (size_t)(n0 + srow) * GK + sgr * 8;

#define STAGE_A(par, h, u) do { \
    const unsigned short* s_ = Ag + (size_t)((h) * 128) * GK + (u) * BK; \
    unsigned short* d_ = Asb + (par) * 16384 + (h) * 8192 + tid * 8; \
    __builtin_amdgcn_global_load_lds((const gvoid*)s_, (lvoid*)d_, 16, 0, 0); \
    __builtin_amdgcn_global_load_lds((const gvoid*)(s_ + (size_t)64 * GK), (lvoid*)(d_ + 4096), 16, 0, 0); \
  } while (0)

#define STAGE_B(par, h, u) do { \
    const unsigned short* s_ = Bg + (size_t)((h) * 128) * GK + (u) * BK; \
    unsigned short* d_ = Bsb + (par) * 16384 + (h) * 8192 + tid * 8; \
    __builtin_amdgcn_global_load_lds((const gvoid*)s_, (lvoid*)d_, 16, 0, 0); \
    __builtin_amdgcn_global_load_lds((const gvoid*)(s_ + (size_t)64 * GK), (lvoid*)(d_ + 4096), 16, 0, 0); \
  } while (0)

  f32x4 acc[8][4];
#pragma unroll
  for (int mi = 0; mi < 8; ++mi)
#pragma unroll
    for (int ni = 0; ni < 4; ++ni)
      acc[mi][ni] = (f32x4){0.f, 0.f, 0.f, 0.f};

  // read bases (element offsets into a buffer)
  const int aBase = wr * 8192 + ln15 * 64;                       // wave's A half + frag row
  const int bBase = (wc >> 1) * 8192 + ((wc & 1) * 64 + ln15) * 64;

  bf16x8 bfr[4][2];  // B frags: [ni][kk], held across the 4 phases of a tile

  // prologue: 12 loads in flight: B(0)->buf0, A(0)->buf0, B(1)->buf1
  STAGE_B(0, 0, 0); STAGE_B(0, 1, 0);
  STAGE_A(0, 0, 0); STAGE_A(0, 1, 0);
  STAGE_B(1, 0, 1); STAGE_B(1, 1, 1);
  asm volatile("s_waitcnt vmcnt(4)" ::: "memory");   // retire B(0), A(0); B(1) stays in flight
  BARRIER();

  for (int t = 0; t < NT; ++t) {
    const int p  = t & 1;
    const int u1 = (t + 1 < NT) ? t + 1 : NT - 1;   // clamp: dead loads land in dead regions
    const int u2 = (t + 2 < NT) ? t + 2 : NT - 1;
    const unsigned short* Ard = Asb + p * 16384 + aBase;
    const unsigned short* Brd = Bsb + p * 16384 + bBase;

    // ---------------- phase 0 (quadrant 0) ----------------
    {
      bf16x8 af[2][2];
#pragma unroll
      for (int mi2 = 0; mi2 < 2; ++mi2)
#pragma unroll
        for (int kk = 0; kk < 2; ++kk)
          af[mi2][kk] = *(const bf16x8*)(Ard + mi2 * 1024 + ck[kk]);
#pragma unroll
      for (int ni = 0; ni < 4; ++ni)
#pragma unroll
        for (int kk = 0; kk < 2; ++kk)
          bfr[ni][kk] = *(const bf16x8*)(Brd + ni * 1024 + ck[kk]);
      STAGE_A(p ^ 1, 0, u1);
      BARRIER();
      __builtin_amdgcn_s_setprio(1);
#pragma unroll
      for (int kk = 0; kk < 2; ++kk)
#pragma unroll
        for (int mi2 = 0; mi2 < 2; ++mi2)
#pragma unroll
          for (int ni = 0; ni < 4; ++ni)
            acc[mi2][ni] = __builtin_amdgcn_mfma_f32_16x16x32_bf16(af[mi2][kk], bfr[ni][kk],
                                                                   acc[mi2][ni], 0, 0, 0);
      __builtin_amdgcn_s_setprio(0);
      BARRIER();
    }

    // ---------------- phases 1..3 (quadrants 1..3) ----------------
#pragma unroll
    for (int q = 1; q < 4; ++q) {
      bf16x8 af[2][2];
#pragma unroll
      for (int mi2 = 0; mi2 < 2; ++mi2)
#pragma unroll
        for (int kk = 0; kk < 2; ++kk)
          af[mi2][kk] = *(const bf16x8*)(Ard + (2 * q + mi2) * 1024 + ck[kk]);
      if (q == 1)      STAGE_A(p ^ 1, 1, u1);
      else if (q == 2) STAGE_B(p, 0, u2);
      else             STAGE_B(p, 1, u2);
      BARRIER();
      __builtin_amdgcn_s_setprio(1);
#pragma unroll
      for (int kk = 0; kk < 2; ++kk)
#pragma unroll
        for (int mi2 = 0; mi2 < 2; ++mi2)
#pragma unroll
          for (int ni = 0; ni < 4; ++ni)
            acc[2 * q + mi2][ni] = __builtin_amdgcn_mfma_f32_16x16x32_bf16(af[mi2][kk], bfr[ni][kk],
                                                                           acc[2 * q + mi2][ni], 0, 0, 0);
      __builtin_amdgcn_s_setprio(0);
      if (q == 3)
        asm volatile("s_waitcnt vmcnt(4)" ::: "memory");  // retire B(t+1), A(t+1) for next ph0
      BARRIER();
    }
  }

  // epilogue: C/D layout col = lane&15, row = quad*4 + reg  [m89/m91 verified]
#pragma unroll
  for (int ni = 0; ni < 4; ++ni) {
    const int col = n0 + wc * 64 + ni * 16 + ln15;
    const float bv = bias[col];
#pragma unroll
    for (int mi = 0; mi < 8; ++mi) {
      const int rowb = m0 + wr * 128 + mi * 16 + quad * 4;
#pragma unroll
      for (int r = 0; r < 4; ++r)
        C[(size_t)(rowb + r) * GN + col] = acc[mi][ni][r] + bv;
    }
  }
#undef STAGE_A
#undef STAGE_B
}

// ---------------- naive fallback (only if ws too small) ----------------
__global__ void naive_kernel(const float* __restrict__ x, const float* __restrict__ a,
                             const float* __restrict__ s, const float* __restrict__ bias,
                             float* __restrict__ out) {
  long long idx = (long long)blockIdx.x * blockDim.x + threadIdx.x;
  if (idx >= (long long)TOKENS * OUT_F) return;
  int t = (int)(idx >> 12);
  int o = (int)(idx & 4095);
  int ib = o >> 10, p = o & 1023;
  float acc = bias[o];
  for (int jb = 0; jb < 4; ++jb) {
    float a0 = a[0  + ib * 4 + jb];
    float a1 = a[16 + ib * 4 + jb];
    float a2 = a[32 + ib * 4 + jb];
    float a3 = a[48 + ib * 4 + jb];
    const float* xr = x + (size_t)t * IN_F + jb * 1024;
    const float* s0 = s + (size_t)p * 1024;
    const float* s1 = s0 + 1048576;
    const float* s2 = s1 + 1048576;
    const float* s3 = s2 + 1048576;
    for (int q = 0; q < 1024; ++q) {
      float w = a0 * s0[q] + a1 * s1[q] + a2 * s2[q] + a3 * s3[q];
      acc += xr[q] * w;
    }
  }
  out[idx] = acc;
}

extern "C" void kernel_launch(void* const* d_in, const int* in_sizes, int n_in,
                              void* d_out, int out_size, void* d_ws, size_t ws_size,
                              hipStream_t stream) {
  const float* x    = (const float*)d_in[0];
  const float* a    = (const float*)d_in[1];
  const float* s    = (const float*)d_in[2];
  const float* bias = (const float*)d_in[3];
  float* out = (float*)d_out;

  const size_t xb_elems = (size_t)TOKENS * IN_F;          // 33.5M bf16 = 67 MB
  const size_t wb_elems = (size_t)OUT_F * IN_F;           // 16.7M bf16 = 33.5 MB
  const size_t need = (xb_elems + wb_elems) * sizeof(unsigned short);

  if (ws_size >= need) {
    unsigned short* Xb = (unsigned short*)d_ws;
    unsigned short* Wb = Xb + xb_elems;
    const int cast_blocks  = (int)(xb_elems / 8 / 256);   // 16384
    const int build_blocks = (int)(wb_elems / 4 / 256);   // 16384
    prep_kernel<<<cast_blocks + build_blocks, 256, 0, stream>>>(
        (const float4*)x, (bf16x8*)Xb, a, s, Wb);
    dim3 grid(GN / BN, TOKENS / BM);                      // (16, 32) = 512 blocks
    gemm_bias_kernel<<<grid, 512, 0, stream>>>(Xb, Wb, bias, out);
  } else {
    long long total = (long long)TOKENS * OUT_F;
    naive_kernel<<<(int)((total + 255) / 256), 256, 0, stream>>>(x, a, s, bias, out);
  }
}

// Round 4
// 520.274 us; speedup vs baseline: 1.1848x; 1.1186x over previous
//
#include <hip/hip_runtime.h>

// Problem constants (QLinear_17918603559229)
#define TOKENS 8192
#define IN_F   4096
#define OUT_F  4096
#define GK     IN_F
#define GN     OUT_F

#define BM 128
#define BN 128
#define BK 64

typedef __attribute__((ext_vector_type(8))) short bf16x8;
typedef __attribute__((ext_vector_type(4))) float f32x4;
typedef __attribute__((address_space(1))) void gvoid;
typedef __attribute__((address_space(3))) void lvoid;

static __device__ __forceinline__ unsigned short f32_to_bf16(float f) {
  union { float f; unsigned int u; } v; v.f = f;
  unsigned int u = v.u;
  return (unsigned short)((u + 0x7FFFu + ((u >> 16) & 1u)) >> 16);  // RNE
}

// ---------------- fused prep: cast x (f32->bf16) + build W (bf16) ----------------
// blocks [0, 16384): cast 8 elems/thread; blocks [16384, 32768): build 4 elems/thread
__global__ void prep_kernel(const float4* __restrict__ x, bf16x8* __restrict__ xb,
                            const float* __restrict__ a, const float* __restrict__ s,
                            unsigned short* __restrict__ wb) {
  const int bid = blockIdx.x;
  if (bid < 16384) {
    const int idx = bid * 256 + threadIdx.x;
    float4 v0 = x[idx * 2];
    float4 v1 = x[idx * 2 + 1];
    bf16x8 r;
    r[0] = (short)f32_to_bf16(v0.x); r[1] = (short)f32_to_bf16(v0.y);
    r[2] = (short)f32_to_bf16(v0.z); r[3] = (short)f32_to_bf16(v0.w);
    r[4] = (short)f32_to_bf16(v1.x); r[5] = (short)f32_to_bf16(v1.y);
    r[6] = (short)f32_to_bf16(v1.z); r[7] = (short)f32_to_bf16(v1.w);
    xb[idx] = r;
  } else {
    const int gid = (bid - 16384) * 256 + threadIdx.x;   // OUT_F * IN_F / 4 threads
    const int o = gid >> 10;
    const int i = (gid & 1023) << 2;                      // 4 consecutive i, same j-block
    const int ib = o >> 10, p = o & 1023;
    const int jb = i >> 10, q = i & 1023;
    float r0 = 0.f, r1 = 0.f, r2 = 0.f, r3 = 0.f;
#pragma unroll
    for (int k = 0; k < 4; ++k) {
      float ak = a[k * 16 + ib * 4 + jb];
      const float4 sv = *(const float4*)(s + (((size_t)(k * 1024 + p)) << 10) + q);
      r0 += ak * sv.x; r1 += ak * sv.y; r2 += ak * sv.z; r3 += ak * sv.w;
    }
    ushort4 w;
    w.x = f32_to_bf16(r0); w.y = f32_to_bf16(r1);
    w.z = f32_to_bf16(r2); w.w = f32_to_bf16(r3);
    *(ushort4*)(wb + ((size_t)o << 12) + i) = w;
  }
}

// ---------------- GEMM: C[M,N] = A[M,K] @ B[N,K]^T + bias, bf16 in / f32 out ----------------
// m97 structure: 128x128 tile, 4 waves, BK=64, global_load_lds width 16,
// mfma_f32_16x16x32_bf16, plus XOR-granule swizzle (applied on the GLOBAL source
// column per lane — LDS side must stay lane-contiguous for global_load_lds).
// Measured here: 245 us, MfmaUtil 55%, bank conflicts 0, ~3 blocks/CU (TLP hides
// the barrier drain — this beats the 1-block/CU 256^2 8-phase port, r2/r3 evidence).
__global__ __launch_bounds__(256, 2)
void gemm_bias_kernel(const unsigned short* __restrict__ A,
                      const unsigned short* __restrict__ B,
                      const float* __restrict__ bias,
                      float* __restrict__ C) {
  __shared__ unsigned short As[BM * BK];   // 16 KB, LDS[row][gran g] = Aglob[row][gran g ^ (row&7)]
  __shared__ unsigned short Bs[BN * BK];   // 16 KB, same swizzle

  const int tid  = threadIdx.x;
  const int lane = tid & 63;
  const int wave = tid >> 6;
  const int m0 = blockIdx.y * BM;
  const int n0 = blockIdx.x * BN;
  const int wm = (wave >> 1) * 64;
  const int wn = (wave & 1) * 64;

  f32x4 acc[4][4];
#pragma unroll
  for (int mi = 0; mi < 4; ++mi)
#pragma unroll
    for (int ni = 0; ni < 4; ++ni)
      acc[mi][ni] = (f32x4){0.f, 0.f, 0.f, 0.f};

  // staging map: pass p covers rows p*32 + (tid>>3); granule (tid&7), swizzled source
  const int srow = tid >> 3;
  const int sgr  = (tid & 7) ^ (srow & 7);
  const unsigned short* Ag = A + (size_t)(m0 + srow) * GK + sgr * 8;
  const unsigned short* Bg = B + (size_t)(n0 + srow) * GK + sgr * 8;
  unsigned short* Asd = As + tid * 8;      // lane-contiguous LDS dest
  unsigned short* Bsd = Bs + tid * 8;

  const int ln15 = lane & 15;
  const int quad = lane >> 4;
  const int sw   = lane & 7;               // == (frag row) & 7
  int rowA[4], rowB[4];
#pragma unroll
  for (int t = 0; t < 4; ++t) {
    rowA[t] = (wm + t * 16 + ln15) * BK;
    rowB[t] = (wn + t * 16 + ln15) * BK;
  }

  for (int k0 = 0; k0 < GK; k0 += BK) {
#pragma unroll
    for (int p = 0; p < 4; ++p) {
      __builtin_amdgcn_global_load_lds((const gvoid*)(Ag + (size_t)(p * 32) * GK + k0),
                                       (lvoid*)(Asd + p * 2048), 16, 0, 0);
      __builtin_amdgcn_global_load_lds((const gvoid*)(Bg + (size_t)(p * 32) * GK + k0),
                                       (lvoid*)(Bsd + p * 2048), 16, 0, 0);
    }
    __syncthreads();
#pragma unroll
    for (int half = 0; half < 2; ++half) {
      const int gk   = half * 4 + quad;          // source granule wanted (k = gk*8 + j)
      const int cofs = ((gk ^ sw) << 3);         // swizzled LDS column (elements)
      bf16x8 af[4], bfr[4];
#pragma unroll
      for (int t = 0; t < 4; ++t) {
        af[t]  = *(const bf16x8*)(As + rowA[t] + cofs);
        bfr[t] = *(const bf16x8*)(Bs + rowB[t] + cofs);
      }
#pragma unroll
      for (int mi = 0; mi < 4; ++mi)
#pragma unroll
        for (int ni = 0; ni < 4; ++ni)
          acc[mi][ni] = __builtin_amdgcn_mfma_f32_16x16x32_bf16(af[mi], bfr[ni],
                                                                acc[mi][ni], 0, 0, 0);
    }
    __syncthreads();
  }

  // epilogue: C/D layout col = lane&15, row = quad*4 + reg  [m89/m91 verified]
#pragma unroll
  for (int ni = 0; ni < 4; ++ni) {
    const int col = n0 + wn + ni * 16 + ln15;
    const float bv = bias[col];
#pragma unroll
    for (int mi = 0; mi < 4; ++mi) {
      const int rowb = m0 + wm + mi * 16 + quad * 4;
#pragma unroll
      for (int r = 0; r < 4; ++r)
        C[(size_t)(rowb + r) * GN + col] = acc[mi][ni][r] + bv;
    }
  }
}

// ---------------- naive fallback (only if ws too small) ----------------
__global__ void naive_kernel(const float* __restrict__ x, const float* __restrict__ a,
                             const float* __restrict__ s, const float* __restrict__ bias,
                             float* __restrict__ out) {
  long long idx = (long long)blockIdx.x * blockDim.x + threadIdx.x;
  if (idx >= (long long)TOKENS * OUT_F) return;
  int t = (int)(idx >> 12);
  int o = (int)(idx & 4095);
  int ib = o >> 10, p = o & 1023;
  float acc = bias[o];
  for (int jb = 0; jb < 4; ++jb) {
    float a0 = a[0  + ib * 4 + jb];
    float a1 = a[16 + ib * 4 + jb];
    float a2 = a[32 + ib * 4 + jb];
    float a3 = a[48 + ib * 4 + jb];
    const float* xr = x + (size_t)t * IN_F + jb * 1024;
    const float* s0 = s + (size_t)p * 1024;
    const float* s1 = s0 + 1048576;
    const float* s2 = s1 + 1048576;
    const float* s3 = s2 + 1048576;
    for (int q = 0; q < 1024; ++q) {
      float w = a0 * s0[q] + a1 * s1[q] + a2 * s2[q] + a3 * s3[q];
      acc += xr[q] * w;
    }
  }
  out[idx] = acc;
}

extern "C" void kernel_launch(void* const* d_in, const int* in_sizes, int n_in,
                              void* d_out, int out_size, void* d_ws, size_t ws_size,
                              hipStream_t stream) {
  const float* x    = (const float*)d_in[0];
  const float* a    = (const float*)d_in[1];
  const float* s    = (const float*)d_in[2];
  const float* bias = (const float*)d_in[3];
  float* out = (float*)d_out;

  const size_t xb_elems = (size_t)TOKENS * IN_F;          // 33.5M bf16 = 67 MB
  const size_t wb_elems = (size_t)OUT_F * IN_F;           // 16.7M bf16 = 33.5 MB
  const size_t need = (xb_elems + wb_elems) * sizeof(unsigned short);

  if (ws_size >= need) {
    unsigned short* Xb = (unsigned short*)d_ws;
    unsigned short* Wb = Xb + xb_elems;
    const int cast_blocks  = (int)(xb_elems / 8 / 256);   // 16384
    const int build_blocks = (int)(wb_elems / 4 / 256);   // 16384
    prep_kernel<<<cast_blocks + build_blocks, 256, 0, stream>>>(
        (const float4*)x, (bf16x8*)Xb, a, s, Wb);
    dim3 grid(GN / BN, TOKENS / BM);                      // (32, 64) = 2048 blocks
    gemm_bias_kernel<<<grid, 256, 0, stream>>>(Xb, Wb, bias, out);
  } else {
    long long total = (long long)TOKENS * OUT_F;
    naive_kernel<<<(int)((total + 255) / 256), 256, 0, stream>>>(x, a, s, bias, out);
  }
}